// Round 1
// baseline (259.444 us; speedup 1.0000x reference)
//
#include <hip/hip_runtime.h>
#include <math.h>

// ---------------------------------------------------------------------------
// MS-SSIM + MSE loss, shapes fixed: (16,3,512,512) f32, 5 pyramid levels.
// Strategy: separable 11-tap Gaussian; per level one fused LDS-tiled kernel
// (halo load -> horizontal conv of 5 fields -> vertical conv + SSIM/CS ->
// block reduce -> partials). avgpool kernels build the pyramid in d_ws.
// A final 1-block kernel reduces all partials in double and writes (loss,
// msssim). No atomics anywhere -> deterministic.
// ---------------------------------------------------------------------------

#define NPLANES 48  // 16 * 3

struct GaussW { float g[11]; };

// ws layout in floats:
//   img1 pyramid: L1 @ 0, L2 @ 3145728, L3 @ 3932160, L4 @ 4128768
//   img2 pyramid: same + 4177920
//   partial pairs: L0 @ 8355840 (12288), L1 @ 8380416 (3072),
//                  L2 @ 8386560 (768), L3 @ 8388096 (192), L4 @ 8388480 (48)
//   mse partials:  @ 8388576 (2048 singles)
#define PYR2_OFF  4177920
#define P_L0      8355840
#define P_L1      8380416
#define P_L2      8386560
#define P_L3      8388096
#define P_L4      8388480
#define P_MSE     8388576
#define N_MSE_BLK 2048

#define C1F 1.0e-4f
#define C2F 9.0e-4f

// ---------------------------------------------------------------------------
__global__ __launch_bounds__(256) void ssim_kernel(
    const float* __restrict__ x1, const float* __restrict__ x2,
    int H, int W, GaussW gw, float* __restrict__ partials)
{
  __shared__ float t1[42][42];
  __shared__ float t2[42][42];
  __shared__ float hf[5][42][32];
  __shared__ float red[2][4];

  const int tid = threadIdx.x;
  const int Ho = H - 10, Wo = W - 10;
  const int plane = blockIdx.z;
  const size_t pbase = (size_t)plane * H * W;
  const int oy0 = blockIdx.y * 32;
  const int ox0 = blockIdx.x * 32;

  // ---- load halo tiles (42x42) of both images ----
  for (int i = tid; i < 42 * 42; i += 256) {
    int r = i / 42, c = i - r * 42;
    int gy = oy0 + r, gx = ox0 + c;
    float a = 0.f, b = 0.f;
    if (gy < H && gx < W) {
      size_t off = pbase + (size_t)gy * W + gx;
      a = x1[off];
      b = x2[off];
    }
    t1[r][c] = a;
    t2[r][c] = b;
  }
  __syncthreads();

  // ---- horizontal 11-tap conv: 5 fields over 42 rows x 32 cols ----
  for (int i = tid; i < 42 * 32; i += 256) {
    int r = i >> 5, c = i & 31;
    float s1 = 0.f, s2 = 0.f, s11 = 0.f, s22 = 0.f, s12 = 0.f;
#pragma unroll
    for (int k = 0; k < 11; ++k) {
      float w = gw.g[k];
      float a = t1[r][c + k];
      float b = t2[r][c + k];
      s1  += w * a;
      s2  += w * b;
      s11 += w * a * a;
      s22 += w * b * b;
      s12 += w * a * b;
    }
    hf[0][r][c] = s1;
    hf[1][r][c] = s2;
    hf[2][r][c] = s11;
    hf[3][r][c] = s22;
    hf[4][r][c] = s12;
  }
  __syncthreads();

  // ---- vertical 11-tap conv + SSIM / CS per output pixel ----
  float ssim_acc = 0.f, cs_acc = 0.f;
  for (int i = tid; i < 32 * 32; i += 256) {
    int r = i >> 5, c = i & 31;
    if (oy0 + r < Ho && ox0 + c < Wo) {
      float mu1 = 0.f, mu2 = 0.f, e11 = 0.f, e22 = 0.f, e12 = 0.f;
#pragma unroll
      for (int k = 0; k < 11; ++k) {
        float w = gw.g[k];
        mu1 += w * hf[0][r + k][c];
        mu2 += w * hf[1][r + k][c];
        e11 += w * hf[2][r + k][c];
        e22 += w * hf[3][r + k][c];
        e12 += w * hf[4][r + k][c];
      }
      float mu1sq = mu1 * mu1, mu2sq = mu2 * mu2, mu12 = mu1 * mu2;
      float s1sq = e11 - mu1sq;
      float s2sq = e22 - mu2sq;
      float s12  = e12 - mu12;
      float v1 = 2.f * s12 + C2F;
      float v2 = s1sq + s2sq + C2F;
      float csv = v1 / v2;
      float ssimv = ((2.f * mu12 + C1F) * v1) / ((mu1sq + mu2sq + C1F) * v2);
      ssim_acc += ssimv;
      cs_acc   += csv;
    }
  }

  // ---- block reduce two floats ----
#pragma unroll
  for (int off = 32; off; off >>= 1) {
    ssim_acc += __shfl_down(ssim_acc, off);
    cs_acc   += __shfl_down(cs_acc, off);
  }
  int wave = tid >> 6, lane = tid & 63;
  if (lane == 0) { red[0][wave] = ssim_acc; red[1][wave] = cs_acc; }
  __syncthreads();
  if (tid == 0) {
    float s = 0.f, c = 0.f;
#pragma unroll
    for (int i = 0; i < 4; ++i) { s += red[0][i]; c += red[1][i]; }
    int bi = (blockIdx.z * gridDim.y + blockIdx.y) * gridDim.x + blockIdx.x;
    partials[2 * bi]     = s;
    partials[2 * bi + 1] = c;
  }
}

// ---------------------------------------------------------------------------
__global__ __launch_bounds__(256) void downsample_kernel(
    const float* __restrict__ s1, const float* __restrict__ s2,
    float* __restrict__ d1, float* __restrict__ d2, int Ho, int Wo)
{
  int plane = blockIdx.y;
  int i = blockIdx.x * 256 + threadIdx.x;
  int np = Ho * Wo;
  if (i >= np) return;
  int y = i / Wo, x = i - y * Wo;
  int Wi = Wo * 2;
  size_t ib = (size_t)plane * (4 * np) + (size_t)(2 * y) * Wi + 2 * x;
  size_t ob = (size_t)plane * np + i;
  d1[ob] = 0.25f * ((s1[ib] + s1[ib + 1]) + (s1[ib + Wi] + s1[ib + Wi + 1]));
  d2[ob] = 0.25f * ((s2[ib] + s2[ib + 1]) + (s2[ib + Wi] + s2[ib + Wi + 1]));
}

// ---------------------------------------------------------------------------
__global__ __launch_bounds__(256) void mse_kernel(
    const float4* __restrict__ a, const float4* __restrict__ b,
    float* __restrict__ partials, int n4)
{
  __shared__ float red[4];
  const int tid = threadIdx.x;
  float acc = 0.f;
  for (int i = blockIdx.x * 256 + tid; i < n4; i += gridDim.x * 256) {
    float4 x = a[i], y = b[i];
    float d0 = x.x - y.x, d1 = x.y - y.y, d2 = x.z - y.z, d3 = x.w - y.w;
    acc += d0 * d0 + d1 * d1 + d2 * d2 + d3 * d3;
  }
#pragma unroll
  for (int off = 32; off; off >>= 1) acc += __shfl_down(acc, off);
  int wave = tid >> 6, lane = tid & 63;
  if (lane == 0) red[wave] = acc;
  __syncthreads();
  if (tid == 0) {
    float s = 0.f;
#pragma unroll
    for (int i = 0; i < 4; ++i) s += red[i];
    partials[blockIdx.x] = s;
  }
}

// ---------------------------------------------------------------------------
__global__ __launch_bounds__(256) void final_kernel(
    const float* __restrict__ ws, float* __restrict__ out)
{
  __shared__ double sred[2][4];
  __shared__ double fin[11];  // ssim[5], cs[5], mse
  const int tid = threadIdx.x;
  const int offs[5] = {P_L0, P_L1, P_L2, P_L3, P_L4};
  const int cnts[5] = {12288, 3072, 768, 192, 48};

  for (int l = 0; l < 5; ++l) {
    double s0 = 0.0, s1 = 0.0;
    for (int i = tid; i < cnts[l]; i += 256) {
      s0 += (double)ws[offs[l] + 2 * i];
      s1 += (double)ws[offs[l] + 2 * i + 1];
    }
#pragma unroll
    for (int off = 32; off; off >>= 1) {
      s0 += __shfl_down(s0, off);
      s1 += __shfl_down(s1, off);
    }
    if ((tid & 63) == 0) { sred[0][tid >> 6] = s0; sred[1][tid >> 6] = s1; }
    __syncthreads();
    if (tid == 0) {
      double a = 0.0, b = 0.0;
      for (int i = 0; i < 4; ++i) { a += sred[0][i]; b += sred[1][i]; }
      fin[l] = a;       // ssim sum
      fin[5 + l] = b;   // cs sum
    }
    __syncthreads();
  }

  {
    double s0 = 0.0;
    for (int i = tid; i < N_MSE_BLK; i += 256) s0 += (double)ws[P_MSE + i];
#pragma unroll
    for (int off = 32; off; off >>= 1) s0 += __shfl_down(s0, off);
    if ((tid & 63) == 0) sred[0][tid >> 6] = s0;
    __syncthreads();
    if (tid == 0) {
      double a = 0.0;
      for (int i = 0; i < 4; ++i) a += sred[0][i];
      fin[10] = a;
    }
    __syncthreads();
  }

  if (tid == 0) {
    const double wts[5] = {0.0448, 0.2856, 0.3001, 0.2363, 0.1333};
    const double dims[5] = {502.0, 246.0, 118.0, 54.0, 22.0};
    double mssim[5], mcs[5];
    for (int l = 0; l < 5; ++l) {
      double n = 48.0 * dims[l] * dims[l];
      mssim[l] = fin[l] / n;
      mcs[l]   = fin[5 + l] / n;
    }
    // literal pytorch_msssim translation: prod(pow1[:-1] * pow2[-1])
    double p2last = pow(mssim[4], wts[4]);
    double prod = 1.0;
    for (int i = 0; i < 4; ++i) prod *= pow(mcs[i], wts[i]) * p2last;
    double msssim = prod;
    double mse = fin[10] / 12582912.0;
    double loss = mse - msssim + 1.0;
    out[0] = (float)loss;
    out[1] = (float)msssim;
  }
}

// ---------------------------------------------------------------------------
extern "C" void kernel_launch(void* const* d_in, const int* in_sizes, int n_in,
                              void* d_out, int out_size, void* d_ws, size_t ws_size,
                              hipStream_t stream)
{
  const float* rec  = (const float*)d_in[0];   // reconst
  const float* orig = (const float*)d_in[1];   // original
  float* ws  = (float*)d_ws;
  float* out = (float*)d_out;

  // Gaussian taps (computed in double like the reference, cast to f32)
  GaussW gw;
  {
    double g[11], s = 0.0;
    for (int i = 0; i < 11; ++i) {
      double x = (double)i - 5.0;
      g[i] = exp(-(x * x) / 4.5);
      s += g[i];
    }
    for (int i = 0; i < 11; ++i) gw.g[i] = (float)(g[i] / s);
  }

  // pyramid pointers (level 0 = inputs; SSIM is symmetric in its args)
  const float* l1[5] = {orig, ws + 0, ws + 3145728, ws + 3932160, ws + 4128768};
  const float* l2[5] = {rec,  ws + PYR2_OFF, ws + PYR2_OFF + 3145728,
                        ws + PYR2_OFF + 3932160, ws + PYR2_OFF + 4128768};
  const int Hs[5]   = {512, 256, 128, 64, 32};
  const int pOff[5] = {P_L0, P_L1, P_L2, P_L3, P_L4};

  // MSE partials
  mse_kernel<<<dim3(N_MSE_BLK), dim3(256), 0, stream>>>(
      (const float4*)rec, (const float4*)orig, ws + P_MSE, 12582912 / 4);

  for (int l = 0; l < 5; ++l) {
    int H = Hs[l];
    int Ho = H - 10;
    int gx = (Ho + 31) / 32;
    dim3 grid(gx, gx, NPLANES);
    ssim_kernel<<<grid, dim3(256), 0, stream>>>(l1[l], l2[l], H, H, gw, ws + pOff[l]);
    if (l < 4) {
      int Hn = H / 2;
      int np = Hn * Hn;
      downsample_kernel<<<dim3((np + 255) / 256, NPLANES), dim3(256), 0, stream>>>(
          l1[l], l2[l], (float*)l1[l + 1], (float*)l2[l + 1], Hn, Hn);
    }
  }

  final_kernel<<<dim3(1), dim3(256), 0, stream>>>(ws, out);
}

// Round 3
// 207.041 us; speedup vs baseline: 1.2531x; 1.2531x over previous
//
#include <hip/hip_runtime.h>
#include <math.h>

// ---------------------------------------------------------------------------
// MS-SSIM + MSE loss, shapes fixed: (16,3,512,512) f32, 5 pyramid levels.
// R3 (= R2 minus dead-code compile error): one fused kernel per level:
// halo-load tile -> (MSE partial @L0, 2x2-avgpool next level) -> separable
// 11-tap conv with register-sliding H-pass (2 px/thread) and V-pass
// (4 rows/thread) -> SSIM/CS -> block reduce -> partials. LDS strides
// padded (43 / 33). Final 1-block kernel reduces in double. No atomics.
// ---------------------------------------------------------------------------

#define NPLANES 48  // 16 * 3

struct GaussW { float g[11]; };

// ws layout in floats:
//   img1 pyramid: L1 @ 0, L2 @ 3145728, L3 @ 3932160, L4 @ 4128768
//   img2 pyramid: same + PYR2_OFF
//   partial pairs: L0 @ 8355840 (12288 pairs), L1 (3072), L2 (768),
//                  L3 (192), L4 (48)
//   mse partials:  @ P_MSE (12288 singles, one per L0 block)
#define PYR2_OFF  4177920
#define P_L0      8355840
#define P_L1      8380416
#define P_L2      8386560
#define P_L3      8388096
#define P_L4      8388480
#define P_MSE     8388576
#define N_MSE_BLK 12288

#define C1F 1.0e-4f
#define C2F 9.0e-4f

// ---------------------------------------------------------------------------
template <int DO_MSE>
__global__ __launch_bounds__(256) void ssim_fused(
    const float* __restrict__ x1, const float* __restrict__ x2,
    int H, GaussW gw, float* __restrict__ partials,
    float* __restrict__ msep, float* __restrict__ d1, float* __restrict__ d2)
{
  __shared__ float t1[42][43];
  __shared__ float t2[42][43];
  __shared__ float hf[5][42][33];
  __shared__ float red[3][4];

  const int tid = threadIdx.x;
  const int Ho = H - 10;
  const int plane = blockIdx.z;
  const size_t pbase = (size_t)plane * H * H;
  const int oy0 = blockIdx.y * 32, ox0 = blockIdx.x * 32;

  // ---- halo load (42x42 of both images, zero-pad past edge) ----
  for (int i = tid; i < 42 * 42; i += 256) {
    int r = i / 42, c = i - r * 42;
    int gy = oy0 + r, gx = ox0 + c;
    float a = 0.f, b = 0.f;
    if (gy < H && gx < H) {
      size_t off = pbase + (size_t)gy * H + gx;
      a = x1[off];
      b = x2[off];
    }
    t1[r][c] = a;
    t2[r][c] = b;
  }
  __syncthreads();

  // ---- fused MSE partial over this block's owned 32x32 input patch ----
  float mse_acc = 0.f;
  if (DO_MSE) {
    for (int i = tid; i < 1024; i += 256) {
      int r = i >> 5, c = i & 31;
      float d = t1[r][c] - t2[r][c];
      mse_acc += d * d;
    }
  }

  // ---- fused 2x2 avgpool: this block owns a 16x16 patch of next level ----
  if (d1) {
    int r = tid >> 4, c = tid & 15;
    float a = 0.25f * ((t1[2 * r][2 * c] + t1[2 * r][2 * c + 1]) +
                       (t1[2 * r + 1][2 * c] + t1[2 * r + 1][2 * c + 1]));
    float b = 0.25f * ((t2[2 * r][2 * c] + t2[2 * r][2 * c + 1]) +
                       (t2[2 * r + 1][2 * c] + t2[2 * r + 1][2 * c + 1]));
    int Hn = H >> 1;
    size_t ob = (size_t)plane * Hn * Hn +
                (size_t)(16 * blockIdx.y + r) * Hn + (16 * blockIdx.x + c);
    d1[ob] = a;
    d2[ob] = b;
  }

  // ---- horizontal 11-tap conv, 2 positions/thread sharing a 12-elem window
  // 672 tasks = 42 rows x 16 col-pairs
  for (int i = tid; i < 672; i += 256) {
    int r = i >> 4, c0 = (i & 15) << 1;
    float a[12], b[12];
#pragma unroll
    for (int j = 0; j < 12; ++j) {
      a[j] = t1[r][c0 + j];
      b[j] = t2[r][c0 + j];
    }
#pragma unroll
    for (int p = 0; p < 2; ++p) {
      float s1 = 0.f, s2 = 0.f, s11 = 0.f, s22 = 0.f, s12 = 0.f;
#pragma unroll
      for (int k = 0; k < 11; ++k) {
        float w = gw.g[k];
        float av = a[k + p], bv = b[k + p];
        float wa = w * av, wb = w * bv;
        s1 += wa;
        s2 += wb;
        s11 += wa * av;
        s22 += wb * bv;
        s12 += wa * bv;
      }
      hf[0][r][c0 + p] = s1;
      hf[1][r][c0 + p] = s2;
      hf[2][r][c0 + p] = s11;
      hf[3][r][c0 + p] = s22;
      hf[4][r][c0 + p] = s12;
    }
  }
  __syncthreads();

  // ---- vertical conv: 4 consecutive rows/thread, hf rows loaded once ----
  const int c = tid & 31, g = tid >> 5;
  float mu1[4], mu2[4], q11[4], q22[4], q12[4];

#define VPASS(FIELD, OUT)                                   \
  {                                                         \
    float h[14];                                            \
    _Pragma("unroll") for (int j = 0; j < 14; ++j)          \
        h[j] = hf[FIELD][4 * g + j][c];                     \
    _Pragma("unroll") for (int r = 0; r < 4; ++r) {         \
      float s = 0.f;                                        \
      _Pragma("unroll") for (int k = 0; k < 11; ++k)        \
          s += gw.g[k] * h[r + k];                          \
      OUT[r] = s;                                           \
    }                                                       \
  }

  VPASS(0, mu1)
  VPASS(1, mu2)
  VPASS(2, q11)
  VPASS(3, q22)
  VPASS(4, q12)
#undef VPASS

  float ssim_acc = 0.f, cs_acc = 0.f;
#pragma unroll
  for (int r = 0; r < 4; ++r) {
    if ((oy0 + 4 * g + r) < Ho && (ox0 + c) < Ho) {  // Wo == Ho (square)
      float m1 = mu1[r], m2 = mu2[r];
      float m1sq = m1 * m1, m2sq = m2 * m2, m12 = m1 * m2;
      float s1sq = q11[r] - m1sq;
      float s2sq = q22[r] - m2sq;
      float s12v = q12[r] - m12;
      float v1 = 2.f * s12v + C2F;
      float v2 = s1sq + s2sq + C2F;
      cs_acc += v1 / v2;
      ssim_acc += ((2.f * m12 + C1F) * v1) / ((m1sq + m2sq + C1F) * v2);
    }
  }

  // ---- block reduce (ssim, cs, mse) ----
#pragma unroll
  for (int off = 32; off; off >>= 1) {
    ssim_acc += __shfl_down(ssim_acc, off);
    cs_acc += __shfl_down(cs_acc, off);
    if (DO_MSE) mse_acc += __shfl_down(mse_acc, off);
  }
  int wave = tid >> 6, lane = tid & 63;
  if (lane == 0) {
    red[0][wave] = ssim_acc;
    red[1][wave] = cs_acc;
    if (DO_MSE) red[2][wave] = mse_acc;
  }
  __syncthreads();
  if (tid == 0) {
    float s = 0.f, cc = 0.f, m = 0.f;
#pragma unroll
    for (int i = 0; i < 4; ++i) {
      s += red[0][i];
      cc += red[1][i];
      if (DO_MSE) m += red[2][i];
    }
    int bi = (blockIdx.z * gridDim.y + blockIdx.y) * gridDim.x + blockIdx.x;
    partials[2 * bi] = s;
    partials[2 * bi + 1] = cc;
    if (DO_MSE) msep[bi] = m;
  }
}

// ---------------------------------------------------------------------------
__global__ __launch_bounds__(256) void final_kernel(
    const float* __restrict__ ws, float* __restrict__ out)
{
  __shared__ double sred[2][4];
  __shared__ double fin[11];  // ssim[5], cs[5], mse
  const int tid = threadIdx.x;
  const int offs[5] = {P_L0, P_L1, P_L2, P_L3, P_L4};
  const int cnts[5] = {12288, 3072, 768, 192, 48};

  for (int l = 0; l < 5; ++l) {
    double s0 = 0.0, s1 = 0.0;
    for (int i = tid; i < cnts[l]; i += 256) {
      s0 += (double)ws[offs[l] + 2 * i];
      s1 += (double)ws[offs[l] + 2 * i + 1];
    }
#pragma unroll
    for (int off = 32; off; off >>= 1) {
      s0 += __shfl_down(s0, off);
      s1 += __shfl_down(s1, off);
    }
    if ((tid & 63) == 0) { sred[0][tid >> 6] = s0; sred[1][tid >> 6] = s1; }
    __syncthreads();
    if (tid == 0) {
      double a = 0.0, b = 0.0;
      for (int i = 0; i < 4; ++i) { a += sred[0][i]; b += sred[1][i]; }
      fin[l] = a;
      fin[5 + l] = b;
    }
    __syncthreads();
  }

  {
    double s0 = 0.0;
    for (int i = tid; i < N_MSE_BLK; i += 256) s0 += (double)ws[P_MSE + i];
#pragma unroll
    for (int off = 32; off; off >>= 1) s0 += __shfl_down(s0, off);
    if ((tid & 63) == 0) sred[0][tid >> 6] = s0;
    __syncthreads();
    if (tid == 0) {
      double a = 0.0;
      for (int i = 0; i < 4; ++i) a += sred[0][i];
      fin[10] = a;
    }
    __syncthreads();
  }

  if (tid == 0) {
    const double wts[5] = {0.0448, 0.2856, 0.3001, 0.2363, 0.1333};
    const double dims[5] = {502.0, 246.0, 118.0, 54.0, 22.0};
    double mssim[5], mcs[5];
    for (int l = 0; l < 5; ++l) {
      double n = 48.0 * dims[l] * dims[l];
      mssim[l] = fin[l] / n;
      mcs[l] = fin[5 + l] / n;
    }
    // literal pytorch_msssim translation: prod(pow1[:-1] * pow2[-1])
    double p2last = pow(mssim[4], wts[4]);
    double prod = 1.0;
    for (int i = 0; i < 4; ++i) prod *= pow(mcs[i], wts[i]) * p2last;
    double msssim = prod;
    double mse = fin[10] / 12582912.0;
    out[0] = (float)(mse - msssim + 1.0);
    out[1] = (float)msssim;
  }
}

// ---------------------------------------------------------------------------
extern "C" void kernel_launch(void* const* d_in, const int* in_sizes, int n_in,
                              void* d_out, int out_size, void* d_ws, size_t ws_size,
                              hipStream_t stream)
{
  const float* rec = (const float*)d_in[0];   // reconst
  const float* orig = (const float*)d_in[1];  // original
  float* ws = (float*)d_ws;
  float* out = (float*)d_out;

  GaussW gw;
  {
    double g[11], s = 0.0;
    for (int i = 0; i < 11; ++i) {
      double x = (double)i - 5.0;
      g[i] = exp(-(x * x) / 4.5);
      s += g[i];
    }
    for (int i = 0; i < 11; ++i) gw.g[i] = (float)(g[i] / s);
  }

  const float* l1[5] = {orig, ws + 0, ws + 3145728, ws + 3932160, ws + 4128768};
  const float* l2[5] = {rec, ws + PYR2_OFF, ws + PYR2_OFF + 3145728,
                        ws + PYR2_OFF + 3932160, ws + PYR2_OFF + 4128768};
  const int Hs[5] = {512, 256, 128, 64, 32};
  const int pOff[5] = {P_L0, P_L1, P_L2, P_L3, P_L4};

  for (int l = 0; l < 5; ++l) {
    int H = Hs[l];
    int gx = H >> 5;  // == ceil((H-10)/32) for all levels here
    dim3 grid(gx, gx, NPLANES);
    float* d1 = (l < 4) ? (float*)l1[l + 1] : nullptr;
    float* d2 = (l < 4) ? (float*)l2[l + 1] : nullptr;
    if (l == 0)
      ssim_fused<1><<<grid, dim3(256), 0, stream>>>(
          l1[l], l2[l], H, gw, ws + pOff[l], ws + P_MSE, d1, d2);
    else
      ssim_fused<0><<<grid, dim3(256), 0, stream>>>(
          l1[l], l2[l], H, gw, ws + pOff[l], nullptr, d1, d2);
  }

  final_kernel<<<dim3(1), dim3(256), 0, stream>>>(ws, out);
}

// Round 4
// 171.794 us; speedup vs baseline: 1.5102x; 1.2052x over previous
//
#include <hip/hip_runtime.h>
#include <math.h>

// ---------------------------------------------------------------------------
// MS-SSIM + MSE loss, shapes fixed: (16,3,512,512) f32, 5 pyramid levels.
// R4: occupancy push. Per-level fused kernel, 32x32 output tile:
//   float4 halo load (42x42, both imgs) -> [MSE + 2x2 avgpool] ->
//   TWO 16-row phases: H-pass into a 26-row ring hf buffer, V-pass
//   (2 rows/thread) + SSIM/CS with rcp math -> block reduce -> partials.
// LDS = 2*42*43*4 + 5*26*33*4 + 48 = 31656 B  => 5 blocks/CU (was 3).
// Final 1-block kernel reduces in double. No atomics.
// ---------------------------------------------------------------------------

#define NPLANES 48  // 16 * 3

struct GaussW { float g[11]; };

// ws layout in floats (unchanged from R3):
#define PYR2_OFF  4177920
#define P_L0      8355840
#define P_L1      8380416
#define P_L2      8386560
#define P_L3      8388096
#define P_L4      8388480
#define P_MSE     8388576
#define N_MSE_BLK 12288

#define C1F 1.0e-4f
#define C2F 9.0e-4f

// ---------------------------------------------------------------------------
template <int DO_MSE>
__global__ __launch_bounds__(256, 5) void ssim_fused(
    const float* __restrict__ x1, const float* __restrict__ x2,
    int H, GaussW gw, float* __restrict__ partials,
    float* __restrict__ msep, float* __restrict__ d1, float* __restrict__ d2)
{
  __shared__ float t1[42][43];      // odd stride: 2-way banks on H reads
  __shared__ float t2[42][43];
  __shared__ float hf[5][26][33];   // ring buffer: slot = row mod 26
  __shared__ float red[3][4];

  const int tid = threadIdx.x;
  const int Ho = H - 10;
  const int plane = blockIdx.z;
  const size_t pbase = (size_t)plane * H * H;
  const int oy0 = blockIdx.y * 32, ox0 = blockIdx.x * 32;

  // ---- halo load: 42 rows x 11 float4 chunks, both images (462 tasks) ----
  for (int i = tid; i < 462; i += 256) {
    int r = i / 11, c4 = i - r * 11;
    int gy = oy0 + r, gx = ox0 + 4 * c4;
    float4 a = {0.f, 0.f, 0.f, 0.f}, b = {0.f, 0.f, 0.f, 0.f};
    if (gy < H && gx < H) {  // gx mult of 4 and < H  =>  gx+3 <= H-1
      const float* pa = x1 + pbase + (size_t)gy * H + gx;
      const float* pb = x2 + pbase + (size_t)gy * H + gx;
      a = *(const float4*)pa;
      b = *(const float4*)pb;
    }
    int c = 4 * c4;
    t1[r][c] = a.x; t1[r][c + 1] = a.y;
    t2[r][c] = b.x; t2[r][c + 1] = b.y;
    if (c4 < 10) {  // chunk 10 only needs cols 40,41 (row width 43)
      t1[r][c + 2] = a.z; t1[r][c + 3] = a.w;
      t2[r][c + 2] = b.z; t2[r][c + 3] = b.w;
    }
  }
  __syncthreads();

  // ---- fused MSE partial over this block's owned 32x32 input patch ----
  float mse_acc = 0.f;
  if (DO_MSE) {
#pragma unroll
    for (int it = 0; it < 4; ++it) {
      int i = tid + 256 * it;
      int r = i >> 5, c = i & 31;
      float dd = t1[r][c] - t2[r][c];
      mse_acc += dd * dd;
    }
  }

  // ---- fused 2x2 avgpool: this block owns a 16x16 patch of next level ----
  if (d1) {
    int r = tid >> 4, c = tid & 15;
    float a = 0.25f * ((t1[2 * r][2 * c] + t1[2 * r][2 * c + 1]) +
                       (t1[2 * r + 1][2 * c] + t1[2 * r + 1][2 * c + 1]));
    float b = 0.25f * ((t2[2 * r][2 * c] + t2[2 * r][2 * c + 1]) +
                       (t2[2 * r + 1][2 * c] + t2[2 * r + 1][2 * c + 1]));
    int Hn = H >> 1;
    size_t ob = (size_t)plane * Hn * Hn +
                (size_t)(16 * blockIdx.y + r) * Hn + (16 * blockIdx.x + c);
    d1[ob] = a;
    d2[ob] = b;
  }

  float ssim_acc = 0.f, cs_acc = 0.f;

  // ---- H-pass: rows [row0, row0+nrows) -> hf slots [slot0, slot0+nrows)
  //      tasks = nrows x 16 col-pairs, 2 px/task sharing a 12-wide window
#define HPASS(ROW0, NROWS)                                                  \
  for (int i = tid; i < (NROWS) * 16; i += 256) {                           \
    int rr = i >> 4, c0 = (i & 15) << 1;                                    \
    int row = (ROW0) + rr;                                                  \
    int slot = ((ROW0) >= 26 ? (ROW0) - 26 : (ROW0)) + rr;                  \
    float a[12], b[12];                                                     \
    _Pragma("unroll") for (int j = 0; j < 12; ++j) {                        \
      a[j] = t1[row][c0 + j];                                               \
      b[j] = t2[row][c0 + j];                                               \
    }                                                                       \
    _Pragma("unroll") for (int p = 0; p < 2; ++p) {                         \
      float s1 = 0.f, s2 = 0.f, s11 = 0.f, s22 = 0.f, s12 = 0.f;            \
      _Pragma("unroll") for (int k = 0; k < 11; ++k) {                      \
        float w = gw.g[k];                                                  \
        float av = a[k + p], bv = b[k + p];                                 \
        float wa = w * av, wb = w * bv;                                     \
        s1 += wa; s2 += wb;                                                 \
        s11 += wa * av; s22 += wb * bv; s12 += wa * bv;                     \
      }                                                                     \
      hf[0][slot][c0 + p] = s1;                                             \
      hf[1][slot][c0 + p] = s2;                                             \
      hf[2][slot][c0 + p] = s11;                                            \
      hf[3][slot][c0 + p] = s22;                                            \
      hf[4][slot][c0 + p] = s12;                                            \
    }                                                                       \
  }

  // ---- V-pass: out rows [Y0, Y0+16), thread = (row-pair, col) ----
#define VPASS(Y0)                                                           \
  {                                                                         \
    int pr = tid >> 5, c = tid & 31;                                        \
    int y0 = (Y0) + 2 * pr;                                                 \
    int slot[12];                                                           \
    _Pragma("unroll") for (int j = 0; j < 12; ++j) {                        \
      int row = y0 + j;                                                     \
      slot[j] = row >= 26 ? row - 26 : row;                                 \
    }                                                                       \
    float o[5][2];                                                          \
    _Pragma("unroll") for (int f = 0; f < 5; ++f) {                         \
      float h[12];                                                          \
      _Pragma("unroll") for (int j = 0; j < 12; ++j)                        \
          h[j] = hf[f][slot[j]][c];                                         \
      float s0 = 0.f, s1 = 0.f;                                             \
      _Pragma("unroll") for (int k = 0; k < 11; ++k) {                      \
        float w = gw.g[k];                                                  \
        s0 += w * h[k];                                                     \
        s1 += w * h[k + 1];                                                 \
      }                                                                     \
      o[f][0] = s0; o[f][1] = s1;                                           \
    }                                                                       \
    _Pragma("unroll") for (int p = 0; p < 2; ++p) {                         \
      if ((oy0 + y0 + p) < Ho && (ox0 + c) < Ho) {                          \
        float m1 = o[0][p], m2 = o[1][p];                                   \
        float m1sq = m1 * m1, m2sq = m2 * m2, m12 = m1 * m2;                \
        float v1 = 2.f * (o[4][p] - m12) + C2F;                             \
        float v2 = (o[2][p] - m1sq) + (o[3][p] - m2sq) + C2F;               \
        float csv = v1 * __builtin_amdgcn_rcpf(v2);                         \
        cs_acc += csv;                                                      \
        ssim_acc += csv * (2.f * m12 + C1F) *                               \
                    __builtin_amdgcn_rcpf(m1sq + m2sq + C1F);               \
      }                                                                     \
    }                                                                       \
  }

  // phase 1: hf rows 0..25, out rows 0..15
  HPASS(0, 26)
  __syncthreads();
  VPASS(0)
  __syncthreads();  // V1 must finish reading slots 0..15 before H2 rewrites
  // phase 2: hf rows 26..41 -> slots 0..15, out rows 16..31
  HPASS(26, 16)
  __syncthreads();
  VPASS(16)

#undef HPASS
#undef VPASS

  // ---- block reduce (ssim, cs, mse) ----
#pragma unroll
  for (int off = 32; off; off >>= 1) {
    ssim_acc += __shfl_down(ssim_acc, off);
    cs_acc += __shfl_down(cs_acc, off);
    if (DO_MSE) mse_acc += __shfl_down(mse_acc, off);
  }
  int wave = tid >> 6, lane = tid & 63;
  if (lane == 0) {
    red[0][wave] = ssim_acc;
    red[1][wave] = cs_acc;
    if (DO_MSE) red[2][wave] = mse_acc;
  }
  __syncthreads();
  if (tid == 0) {
    float s = 0.f, cc = 0.f, m = 0.f;
#pragma unroll
    for (int i = 0; i < 4; ++i) {
      s += red[0][i];
      cc += red[1][i];
      if (DO_MSE) m += red[2][i];
    }
    int bi = (blockIdx.z * gridDim.y + blockIdx.y) * gridDim.x + blockIdx.x;
    partials[2 * bi] = s;
    partials[2 * bi + 1] = cc;
    if (DO_MSE) msep[bi] = m;
  }
}

// ---------------------------------------------------------------------------
__global__ __launch_bounds__(256) void final_kernel(
    const float* __restrict__ ws, float* __restrict__ out)
{
  __shared__ double sred[2][4];
  __shared__ double fin[11];  // ssim[5], cs[5], mse
  const int tid = threadIdx.x;
  const int offs[5] = {P_L0, P_L1, P_L2, P_L3, P_L4};
  const int cnts[5] = {12288, 3072, 768, 192, 48};

  for (int l = 0; l < 5; ++l) {
    double s0 = 0.0, s1 = 0.0;
    for (int i = tid; i < cnts[l]; i += 256) {
      s0 += (double)ws[offs[l] + 2 * i];
      s1 += (double)ws[offs[l] + 2 * i + 1];
    }
#pragma unroll
    for (int off = 32; off; off >>= 1) {
      s0 += __shfl_down(s0, off);
      s1 += __shfl_down(s1, off);
    }
    if ((tid & 63) == 0) { sred[0][tid >> 6] = s0; sred[1][tid >> 6] = s1; }
    __syncthreads();
    if (tid == 0) {
      double a = 0.0, b = 0.0;
      for (int i = 0; i < 4; ++i) { a += sred[0][i]; b += sred[1][i]; }
      fin[l] = a;
      fin[5 + l] = b;
    }
    __syncthreads();
  }

  {
    double s0 = 0.0;
    for (int i = tid; i < N_MSE_BLK; i += 256) s0 += (double)ws[P_MSE + i];
#pragma unroll
    for (int off = 32; off; off >>= 1) s0 += __shfl_down(s0, off);
    if ((tid & 63) == 0) sred[0][tid >> 6] = s0;
    __syncthreads();
    if (tid == 0) {
      double a = 0.0;
      for (int i = 0; i < 4; ++i) a += sred[0][i];
      fin[10] = a;
    }
    __syncthreads();
  }

  if (tid == 0) {
    const double wts[5] = {0.0448, 0.2856, 0.3001, 0.2363, 0.1333};
    const double dims[5] = {502.0, 246.0, 118.0, 54.0, 22.0};
    double mssim[5], mcs[5];
    for (int l = 0; l < 5; ++l) {
      double n = 48.0 * dims[l] * dims[l];
      mssim[l] = fin[l] / n;
      mcs[l] = fin[5 + l] / n;
    }
    // literal pytorch_msssim translation: prod(pow1[:-1] * pow2[-1])
    double p2last = pow(mssim[4], wts[4]);
    double prod = 1.0;
    for (int i = 0; i < 4; ++i) prod *= pow(mcs[i], wts[i]) * p2last;
    double msssim = prod;
    double mse = fin[10] / 12582912.0;
    out[0] = (float)(mse - msssim + 1.0);
    out[1] = (float)msssim;
  }
}

// ---------------------------------------------------------------------------
extern "C" void kernel_launch(void* const* d_in, const int* in_sizes, int n_in,
                              void* d_out, int out_size, void* d_ws, size_t ws_size,
                              hipStream_t stream)
{
  const float* rec = (const float*)d_in[0];   // reconst
  const float* orig = (const float*)d_in[1];  // original
  float* ws = (float*)d_ws;
  float* out = (float*)d_out;

  GaussW gw;
  {
    double g[11], s = 0.0;
    for (int i = 0; i < 11; ++i) {
      double x = (double)i - 5.0;
      g[i] = exp(-(x * x) / 4.5);
      s += g[i];
    }
    for (int i = 0; i < 11; ++i) gw.g[i] = (float)(g[i] / s);
  }

  const float* l1[5] = {orig, ws + 0, ws + 3145728, ws + 3932160, ws + 4128768};
  const float* l2[5] = {rec, ws + PYR2_OFF, ws + PYR2_OFF + 3145728,
                        ws + PYR2_OFF + 3932160, ws + PYR2_OFF + 4128768};
  const int Hs[5] = {512, 256, 128, 64, 32};
  const int pOff[5] = {P_L0, P_L1, P_L2, P_L3, P_L4};

  for (int l = 0; l < 5; ++l) {
    int H = Hs[l];
    int gx = H >> 5;
    dim3 grid(gx, gx, NPLANES);
    float* d1 = (l < 4) ? (float*)l1[l + 1] : nullptr;
    float* d2 = (l < 4) ? (float*)l2[l + 1] : nullptr;
    if (l == 0)
      ssim_fused<1><<<grid, dim3(256), 0, stream>>>(
          l1[l], l2[l], H, gw, ws + pOff[l], ws + P_MSE, d1, d2);
    else
      ssim_fused<0><<<grid, dim3(256), 0, stream>>>(
          l1[l], l2[l], H, gw, ws + pOff[l], nullptr, d1, d2);
  }

  final_kernel<<<dim3(1), dim3(256), 0, stream>>>(ws, out);
}